// Round 4
// baseline (186.294 us; speedup 1.0000x reference)
//
#include <hip/hip_runtime.h>
#include <hip/hip_bf16.h>
#include <cstdint>

// ---------- types / helpers ----------
typedef __attribute__((ext_vector_type(8))) short  short8;
typedef __attribute__((ext_vector_type(8))) __bf16 bf16x8;
typedef __attribute__((ext_vector_type(4))) float  floatx4;
typedef __attribute__((ext_vector_type(4))) float  f32x4;
typedef __attribute__((ext_vector_type(4))) short  short4v;

union Frag { short8 s; bf16x8 b; };

__device__ inline short f2bf(float f) {
    union { float f; unsigned u; } v; v.f = f;
    unsigned r = (v.u + 0x7fffu + ((v.u >> 16) & 1u)) >> 16;  // RNE
    return (short)r;
}
__device__ inline float elu(float x) { return x > 0.f ? x : __expf(x) - 1.f; }

__device__ inline short8 load8_f32_to_bf16(const float* __restrict__ p) {
    float4 f0 = ((const float4*)p)[0];
    float4 f1 = ((const float4*)p)[1];
    short8 r;
    r[0] = f2bf(f0.x); r[1] = f2bf(f0.y); r[2] = f2bf(f0.z); r[3] = f2bf(f0.w);
    r[4] = f2bf(f1.x); r[5] = f2bf(f1.y); r[6] = f2bf(f1.z); r[7] = f2bf(f1.w);
    return r;
}

__device__ inline f32x4 ntload4(const f32x4* __restrict__ p) {
    return __builtin_nontemporal_load(p);
}
__device__ inline float ntload1(const float* __restrict__ p) {
    return __builtin_nontemporal_load(p);
}

// ---------- constants ----------
#define B_SZ   4096
#define Z_DIM  256
#define H_DIM  1024
#define OUT_W  33
// option packing offsets (SIZES = [16384,64,4096,64,2048,32])
#define OFF_W1 0
#define OFF_B1 16384
#define OFF_W2 16448
#define OFF_B2 20544
#define OFF_W3 20608
#define OFF_B3 22656
#define OPT_W  22688

#define HYP_K1 1536                 // hyper samples done in kernel 1
#define G_BLOCKS 256                // 128x128 tiles: (4096/128) x (1024/128)
#define CONV_BLOCKS 64

// ---------- shared 128x128 MFMA gemm tile (4 waves 2x2, 4x4 frags) ----------
template<int KTOT, bool ACONV, bool BCONV, bool VEPI>
__device__ __forceinline__ void gemm_tile(
    const void* __restrict__ Av, const void* __restrict__ Bv,
    const float* __restrict__ bias, const float* __restrict__ w3,
    __hip_bfloat16* __restrict__ T, float* __restrict__ out,
    int bm, int bn, int tid)
{
    const int lane = tid & 63, wid = tid >> 6;
    const int wm = wid >> 1, wn = wid & 1;
    const int m_wave = bm * 128 + wm * 64;
    const int n_wave = bn * 128 + wn * 64;
    const int lr = lane & 15, lk = (lane >> 4) * 8;

    floatx4 acc[4][4] = {};
    for (int k0 = 0; k0 < KTOT; k0 += 32) {
        Frag a[4], bb[4];
#pragma unroll
        for (int sm = 0; sm < 4; ++sm) {
            const size_t off = (size_t)(m_wave + sm * 16 + lr) * KTOT + k0 + lk;
            if constexpr (ACONV) a[sm].s = load8_f32_to_bf16((const float*)Av + off);
            else                 a[sm].s = *(const short8*)((const ushort*)Av + off);
        }
#pragma unroll
        for (int sn = 0; sn < 4; ++sn) {
            const size_t off = (size_t)(n_wave + sn * 16 + lr) * KTOT + k0 + lk;
            if constexpr (BCONV) bb[sn].s = load8_f32_to_bf16((const float*)Bv + off);
            else                 bb[sn].s = *(const short8*)((const ushort*)Bv + off);
        }
#pragma unroll
        for (int sm = 0; sm < 4; ++sm)
#pragma unroll
            for (int sn = 0; sn < 4; ++sn)
                acc[sm][sn] = __builtin_amdgcn_mfma_f32_16x16x32_bf16(
                    a[sm].b, bb[sn].b, acc[sm][sn], 0, 0, 0);
    }

    if constexpr (VEPI) {
        float bias_v[4], w3_v[4];
#pragma unroll
        for (int sn = 0; sn < 4; ++sn) {
            const int n = n_wave + sn * 16 + lr;
            bias_v[sn] = bias[n];
            w3_v[sn]   = w3[n];
        }
#pragma unroll
        for (int sm = 0; sm < 4; ++sm) {
#pragma unroll
            for (int r = 0; r < 4; ++r) {
                float rowsum = 0.f;
#pragma unroll
                for (int sn = 0; sn < 4; ++sn)
                    rowsum += elu(acc[sm][sn][r] + bias_v[sn]) * w3_v[sn];
                rowsum += __shfl_xor(rowsum, 1);
                rowsum += __shfl_xor(rowsum, 2);
                rowsum += __shfl_xor(rowsum, 4);
                rowsum += __shfl_xor(rowsum, 8);
                if (lr == 0) {
                    const int m = m_wave + sm * 16 + (lane >> 4) * 4 + r;
                    atomicAdd(out + (size_t)m * OUT_W, rowsum);
                }
            }
        }
    } else {
#pragma unroll
        for (int sm = 0; sm < 4; ++sm)
#pragma unroll
            for (int sn = 0; sn < 4; ++sn) {
                const int n = n_wave + sn * 16 + lr;
                const float bv = bias[n];
#pragma unroll
                for (int r = 0; r < 4; ++r) {
                    const int m = m_wave + sm * 16 + (lane >> 4) * 4 + r;
                    T[(size_t)m * H_DIM + n] = __float2bfloat16(elu(acc[sm][sn][r] + bv));
                }
            }
    }
}

// ---------- hypernet: ONE WAVE per sample, no barriers, NT loads ----------
// h1/h2 are wave-private LDS (lockstep wave64 -> no barrier needed).
__device__ __forceinline__ void hyper_wave(
    const float* __restrict__ z, const float* __restrict__ opt,
    float* __restrict__ out, int b, int lane,
    float* __restrict__ h1, float* __restrict__ h2)
{
    const float* __restrict__ orow = opt + (size_t)b * OPT_W;

    // lane owns z cols 4*lane..4*lane+3
    const f32x4 z4 = *(const f32x4*)(z + (size_t)b * Z_DIM + 4 * lane);

    // ---- layer 1: [64,256] @ z -> h1, relu. 4 chunks of 16 rows, ping-pong ----
    {
        const f32x4* W = (const f32x4*)(orow + OFF_W1);  // row r at W[r*64..]
        f32x4 wa[16], wb[16];
#pragma unroll
        for (int j = 0; j < 16; ++j) wa[j] = ntload4(W + j * 64 + lane);
#pragma unroll
        for (int c = 0; c < 4; ++c) {
            f32x4* cur = (c & 1) ? wb : wa;
            f32x4* nxt = (c & 1) ? wa : wb;
            if (c < 3) {
#pragma unroll
                for (int j = 0; j < 16; ++j)
                    nxt[j] = ntload4(W + ((c + 1) * 16 + j) * 64 + lane);
            }
#pragma unroll
            for (int j = 0; j < 16; ++j) {
                float p = cur[j].x * z4.x + cur[j].y * z4.y +
                          cur[j].z * z4.z + cur[j].w * z4.w;
                p += __shfl_xor(p, 1);  p += __shfl_xor(p, 2);
                p += __shfl_xor(p, 4);  p += __shfl_xor(p, 8);
                p += __shfl_xor(p, 16); p += __shfl_xor(p, 32);
                const int r = c * 16 + j;
                if (lane == 0)
                    h1[r] = fmaxf(p + ntload1(orow + OFF_B1 + r), 0.f);
            }
        }
    }

    // ---- layer 2: [64,64] @ h1 -> h2, relu. 16-lane groups, 4 rows/iter ----
    {
        const f32x4 h1v = *(const f32x4*)(h1 + 4 * (lane & 15));
        const f32x4* W = (const f32x4*)(orow + OFF_W2);
        f32x4 wv[16];
#pragma unroll
        for (int j = 0; j < 16; ++j) wv[j] = ntload4(W + j * 64 + lane);
#pragma unroll
        for (int j = 0; j < 16; ++j) {
            float p = wv[j].x * h1v.x + wv[j].y * h1v.y +
                      wv[j].z * h1v.z + wv[j].w * h1v.w;
            p += __shfl_xor(p, 1); p += __shfl_xor(p, 2);
            p += __shfl_xor(p, 4); p += __shfl_xor(p, 8);
            const int r = j * 4 + (lane >> 4);
            if ((lane & 15) == 0)
                h2[r] = fmaxf(p + ntload1(orow + OFF_B2 + r), 0.f);
        }
    }

    // ---- layer 3: [32,64] @ h2 -> action. 8 iters, 4 rows/iter ----
    {
        const f32x4 h2v = *(const f32x4*)(h2 + 4 * (lane & 15));
        const f32x4* W = (const f32x4*)(orow + OFF_W3);
        f32x4 wv[8];
#pragma unroll
        for (int j = 0; j < 8; ++j) wv[j] = ntload4(W + j * 64 + lane);
#pragma unroll
        for (int j = 0; j < 8; ++j) {
            float p = wv[j].x * h2v.x + wv[j].y * h2v.y +
                      wv[j].z * h2v.z + wv[j].w * h2v.w;
            p += __shfl_xor(p, 1); p += __shfl_xor(p, 2);
            p += __shfl_xor(p, 4); p += __shfl_xor(p, 8);
            const int r = j * 4 + (lane >> 4);
            if ((lane & 15) == 0)
                out[(size_t)b * OUT_W + 1 + r] = p + ntload1(orow + OFF_B3 + r);
        }
    }
}

// ---------- kernel 1: gemm1 + w2conv + col0-init + hyper[0:HYP_K1) ----------
__global__ __launch_bounds__(256) void k1_kernel(
    const float* __restrict__ z, const float* __restrict__ opt,
    const float* __restrict__ w1, const float* __restrict__ b1,
    const float* __restrict__ w2, const float* __restrict__ b3,
    __hip_bfloat16* __restrict__ T1, __hip_bfloat16* __restrict__ w2bf,
    float* __restrict__ out)
{
    __shared__ float hbuf[4][128];
    const int blk = blockIdx.x, t = threadIdx.x;

    if (blk < G_BLOCKS) {
        gemm_tile<Z_DIM, true, true, false>(z, w1, b1, nullptr, T1, nullptr,
                                            blk >> 3, blk & 7, t);
    } else if (blk < G_BLOCKS + CONV_BLOCKS) {
        const int gtid = (blk - G_BLOCKS) * 256 + t;  // 0..16383
        if (gtid < B_SZ) out[(size_t)gtid * OUT_W] = b3[0];  // init value col
#pragma unroll
        for (int i = 0; i < 16; ++i) {
            const int v = gtid + i * 16384;           // float4 index < 262144
            float4 f = ((const float4*)w2)[v];
            short4v s;
            s[0] = f2bf(f.x); s[1] = f2bf(f.y); s[2] = f2bf(f.z); s[3] = f2bf(f.w);
            ((short4v*)w2bf)[v] = s;
        }
    } else {
        const int wid = t >> 6, lane = t & 63;
        const int b = (blk - (G_BLOCKS + CONV_BLOCKS)) * 4 + wid;
        hyper_wave(z, opt, out, b, lane, hbuf[wid], hbuf[wid] + 64);
    }
}

// ---------- kernel 2: gemm2+value + hyper[HYP_K1:B_SZ) ----------
__global__ __launch_bounds__(256) void k2_kernel(
    const float* __restrict__ z, const float* __restrict__ opt,
    const __hip_bfloat16* __restrict__ T1, const __hip_bfloat16* __restrict__ w2bf,
    const float* __restrict__ b2, const float* __restrict__ w3,
    float* __restrict__ out)
{
    __shared__ float hbuf[4][128];
    const int blk = blockIdx.x, t = threadIdx.x;

    if (blk < G_BLOCKS) {
        gemm_tile<H_DIM, false, false, true>(T1, w2bf, b2, w3, nullptr, out,
                                             blk >> 3, blk & 7, t);
    } else {
        const int wid = t >> 6, lane = t & 63;
        const int b = HYP_K1 + (blk - G_BLOCKS) * 4 + wid;
        hyper_wave(z, opt, out, b, lane, hbuf[wid], hbuf[wid] + 64);
    }
}

// ---------- launcher ----------
extern "C" void kernel_launch(void* const* d_in, const int* in_sizes, int n_in,
                              void* d_out, int out_size, void* d_ws, size_t ws_size,
                              hipStream_t stream)
{
    const float* z   = (const float*)d_in[0];
    const float* opt = (const float*)d_in[1];
    const float* w1  = (const float*)d_in[2];
    const float* b1  = (const float*)d_in[3];
    const float* w2  = (const float*)d_in[4];
    const float* b2  = (const float*)d_in[5];
    const float* w3  = (const float*)d_in[6];
    const float* b3  = (const float*)d_in[7];
    float* out = (float*)d_out;

    __hip_bfloat16* T1   = (__hip_bfloat16*)d_ws;  // 8 MB
    __hip_bfloat16* w2bf = (__hip_bfloat16*)((char*)d_ws +
                             (size_t)B_SZ * H_DIM * sizeof(__hip_bfloat16));  // 2 MB

    k1_kernel<<<dim3(G_BLOCKS + CONV_BLOCKS + HYP_K1 / 4), dim3(256), 0, stream>>>(
        z, opt, w1, b1, w2, b3, T1, w2bf, out);

    k2_kernel<<<dim3(G_BLOCKS + (B_SZ - HYP_K1) / 4), dim3(256), 0, stream>>>(
        z, opt, T1, w2bf, b2, w3, out);
}

// Round 5
// 143.656 us; speedup vs baseline: 1.2968x; 1.2968x over previous
//
#include <hip/hip_runtime.h>
#include <hip/hip_bf16.h>
#include <cstdint>

// ---------- types / helpers ----------
typedef __attribute__((ext_vector_type(8))) short  short8;
typedef __attribute__((ext_vector_type(8))) __bf16 bf16x8;
typedef __attribute__((ext_vector_type(4))) float  floatx4;
typedef __attribute__((ext_vector_type(4))) float  f32x4;
typedef __attribute__((ext_vector_type(4))) short  short4v;

union Frag { short8 s; bf16x8 b; };

__device__ inline short f2bf(float f) {
    union { float f; unsigned u; } v; v.f = f;
    unsigned r = (v.u + 0x7fffu + ((v.u >> 16) & 1u)) >> 16;  // RNE
    return (short)r;
}
__device__ inline float elu(float x) { return x > 0.f ? x : __expf(x) - 1.f; }

__device__ inline short8 load8_f32_to_bf16(const float* __restrict__ p) {
    float4 f0 = ((const float4*)p)[0];
    float4 f1 = ((const float4*)p)[1];
    short8 r;
    r[0] = f2bf(f0.x); r[1] = f2bf(f0.y); r[2] = f2bf(f0.z); r[3] = f2bf(f0.w);
    r[4] = f2bf(f1.x); r[5] = f2bf(f1.y); r[6] = f2bf(f1.z); r[7] = f2bf(f1.w);
    return r;
}

// ---------- constants ----------
#define B_SZ   4096
#define Z_DIM  256
#define H_DIM  1024
#define OUT_W  33
// option packing offsets (SIZES = [16384,64,4096,64,2048,32])
#define OFF_W1 0
#define OFF_B1 16384
#define OFF_W2 16448
#define OFF_B2 20544
#define OFF_W3 20608
#define OFF_B3 22656
#define OPT_W  22688

#define HYP_K1 2048                 // hyper samples done in kernel 1
#define G_BLOCKS 256                // 128x128 tiles: (4096/128) x (1024/128)
#define CONV_BLOCKS 64

// ---------- shared 128x128 MFMA gemm tile (4 waves 2x2, 4x4 frags) ----------
template<int KTOT, bool ACONV, bool BCONV, bool VEPI>
__device__ __forceinline__ void gemm_tile(
    const void* __restrict__ Av, const void* __restrict__ Bv,
    const float* __restrict__ bias, const float* __restrict__ w3,
    __hip_bfloat16* __restrict__ T, float* __restrict__ out,
    int bm, int bn, int tid)
{
    const int lane = tid & 63, wid = tid >> 6;
    const int wm = wid >> 1, wn = wid & 1;
    const int m_wave = bm * 128 + wm * 64;
    const int n_wave = bn * 128 + wn * 64;
    const int lr = lane & 15, lk = (lane >> 4) * 8;

    floatx4 acc[4][4] = {};
    for (int k0 = 0; k0 < KTOT; k0 += 32) {
        Frag a[4], bb[4];
#pragma unroll
        for (int sm = 0; sm < 4; ++sm) {
            const size_t off = (size_t)(m_wave + sm * 16 + lr) * KTOT + k0 + lk;
            if constexpr (ACONV) a[sm].s = load8_f32_to_bf16((const float*)Av + off);
            else                 a[sm].s = *(const short8*)((const ushort*)Av + off);
        }
#pragma unroll
        for (int sn = 0; sn < 4; ++sn) {
            const size_t off = (size_t)(n_wave + sn * 16 + lr) * KTOT + k0 + lk;
            if constexpr (BCONV) bb[sn].s = load8_f32_to_bf16((const float*)Bv + off);
            else                 bb[sn].s = *(const short8*)((const ushort*)Bv + off);
        }
#pragma unroll
        for (int sm = 0; sm < 4; ++sm)
#pragma unroll
            for (int sn = 0; sn < 4; ++sn)
                acc[sm][sn] = __builtin_amdgcn_mfma_f32_16x16x32_bf16(
                    a[sm].b, bb[sn].b, acc[sm][sn], 0, 0, 0);
    }

    if constexpr (VEPI) {
        float bias_v[4], w3_v[4];
#pragma unroll
        for (int sn = 0; sn < 4; ++sn) {
            const int n = n_wave + sn * 16 + lr;
            bias_v[sn] = bias[n];
            w3_v[sn]   = w3[n];
        }
#pragma unroll
        for (int sm = 0; sm < 4; ++sm) {
#pragma unroll
            for (int r = 0; r < 4; ++r) {
                float rowsum = 0.f;
#pragma unroll
                for (int sn = 0; sn < 4; ++sn)
                    rowsum += elu(acc[sm][sn][r] + bias_v[sn]) * w3_v[sn];
                rowsum += __shfl_xor(rowsum, 1);
                rowsum += __shfl_xor(rowsum, 2);
                rowsum += __shfl_xor(rowsum, 4);
                rowsum += __shfl_xor(rowsum, 8);
                if (lr == 0) {
                    const int m = m_wave + sm * 16 + (lane >> 4) * 4 + r;
                    atomicAdd(out + (size_t)m * OUT_W, rowsum);
                }
            }
        }
    } else {
#pragma unroll
        for (int sm = 0; sm < 4; ++sm)
#pragma unroll
            for (int sn = 0; sn < 4; ++sn) {
                const int n = n_wave + sn * 16 + lr;
                const float bv = bias[n];
#pragma unroll
                for (int r = 0; r < 4; ++r) {
                    const int m = m_wave + sm * 16 + (lane >> 4) * 4 + r;
                    T[(size_t)m * H_DIM + n] = __float2bfloat16(elu(acc[sm][sn][r] + bv));
                }
            }
    }
}

// ---------- hypernet: one wave per sample, barrier-free, single-buffered ----------
// Coalesced: every weight load instr reads a contiguous 1KB wave segment.
// h1/h2 are wave-private LDS slices; intra-wave dep handled by lgkmcnt.
__device__ __forceinline__ void hyper_wave(
    const float* __restrict__ z, const float* __restrict__ opt,
    float* __restrict__ out, int b, int lane,
    float* __restrict__ h1, float* __restrict__ h2)
{
    const float* __restrict__ orow = opt + (size_t)b * OPT_W;

    // lane owns z cols 4*lane..4*lane+3
    const f32x4 z4 = *(const f32x4*)(z + (size_t)b * Z_DIM + 4 * lane);

    // ---- layer 1: [64,256] @ z -> h1, relu. 4 chunks of 16 rows ----
    {
        const f32x4* W = (const f32x4*)(orow + OFF_W1);   // row r at W[r*64 + lane]
#pragma unroll
        for (int c = 0; c < 4; ++c) {
            f32x4 wv[16];
#pragma unroll
            for (int j = 0; j < 16; ++j)
                wv[j] = W[(c * 16 + j) * 64 + lane];
#pragma unroll
            for (int j = 0; j < 16; ++j) {
                float p = wv[j].x * z4.x + wv[j].y * z4.y +
                          wv[j].z * z4.z + wv[j].w * z4.w;
                p += __shfl_xor(p, 1);  p += __shfl_xor(p, 2);
                p += __shfl_xor(p, 4);  p += __shfl_xor(p, 8);
                p += __shfl_xor(p, 16); p += __shfl_xor(p, 32);
                const int r = c * 16 + j;
                if (lane == 0)
                    h1[r] = fmaxf(p + orow[OFF_B1 + r], 0.f);
            }
        }
    }

    // ---- layer 2: [64,64] @ h1 -> h2, relu. 16 instrs, 4 rows each ----
    {
        const f32x4 h1v = *(const f32x4*)(h1 + 4 * (lane & 15));
        const f32x4* W = (const f32x4*)(orow + OFF_W2);
        f32x4 wv[16];
#pragma unroll
        for (int j = 0; j < 16; ++j) wv[j] = W[j * 64 + lane];
#pragma unroll
        for (int j = 0; j < 16; ++j) {
            float p = wv[j].x * h1v.x + wv[j].y * h1v.y +
                      wv[j].z * h1v.z + wv[j].w * h1v.w;
            p += __shfl_xor(p, 1); p += __shfl_xor(p, 2);
            p += __shfl_xor(p, 4); p += __shfl_xor(p, 8);
            const int r = j * 4 + (lane >> 4);
            if ((lane & 15) == 0)
                h2[r] = fmaxf(p + orow[OFF_B2 + r], 0.f);
        }
    }

    // ---- layer 3: [32,64] @ h2 -> action. 8 instrs, 4 rows each ----
    {
        const f32x4 h2v = *(const f32x4*)(h2 + 4 * (lane & 15));
        const f32x4* W = (const f32x4*)(orow + OFF_W3);
        f32x4 wv[8];
#pragma unroll
        for (int j = 0; j < 8; ++j) wv[j] = W[j * 64 + lane];
#pragma unroll
        for (int j = 0; j < 8; ++j) {
            float p = wv[j].x * h2v.x + wv[j].y * h2v.y +
                      wv[j].z * h2v.z + wv[j].w * h2v.w;
            p += __shfl_xor(p, 1); p += __shfl_xor(p, 2);
            p += __shfl_xor(p, 4); p += __shfl_xor(p, 8);
            const int r = j * 4 + (lane >> 4);
            if ((lane & 15) == 0)
                out[(size_t)b * OUT_W + 1 + r] = p + orow[OFF_B3 + r];
        }
    }
}

// ---------- kernel 1: gemm1 + w2conv + col0-init + hyper[0:HYP_K1) ----------
__global__ __launch_bounds__(256) void k1_kernel(
    const float* __restrict__ z, const float* __restrict__ opt,
    const float* __restrict__ w1, const float* __restrict__ b1,
    const float* __restrict__ w2, const float* __restrict__ b3,
    __hip_bfloat16* __restrict__ T1, __hip_bfloat16* __restrict__ w2bf,
    float* __restrict__ out)
{
    __shared__ float hbuf[4][128];
    const int blk = blockIdx.x, t = threadIdx.x;

    if (blk < G_BLOCKS) {
        gemm_tile<Z_DIM, true, true, false>(z, w1, b1, nullptr, T1, nullptr,
                                            blk >> 3, blk & 7, t);
    } else if (blk < G_BLOCKS + CONV_BLOCKS) {
        const int gtid = (blk - G_BLOCKS) * 256 + t;  // 0..16383
        if (gtid < B_SZ) out[(size_t)gtid * OUT_W] = b3[0];  // init value col
#pragma unroll
        for (int i = 0; i < 16; ++i) {
            const int v = gtid + i * 16384;           // float4 index < 262144
            float4 f = ((const float4*)w2)[v];
            short4v s;
            s[0] = f2bf(f.x); s[1] = f2bf(f.y); s[2] = f2bf(f.z); s[3] = f2bf(f.w);
            ((short4v*)w2bf)[v] = s;
        }
    } else {
        const int wid = t >> 6, lane = t & 63;
        const int b = (blk - (G_BLOCKS + CONV_BLOCKS)) * 4 + wid;
        hyper_wave(z, opt, out, b, lane, hbuf[wid], hbuf[wid] + 64);
    }
}

// ---------- kernel 2: gemm2+value + hyper[HYP_K1:B_SZ) ----------
__global__ __launch_bounds__(256) void k2_kernel(
    const float* __restrict__ z, const float* __restrict__ opt,
    const __hip_bfloat16* __restrict__ T1, const __hip_bfloat16* __restrict__ w2bf,
    const float* __restrict__ b2, const float* __restrict__ w3,
    float* __restrict__ out)
{
    __shared__ float hbuf[4][128];
    const int blk = blockIdx.x, t = threadIdx.x;

    if (blk < G_BLOCKS) {
        gemm_tile<H_DIM, false, false, true>(T1, w2bf, b2, w3, nullptr, out,
                                             blk >> 3, blk & 7, t);
    } else {
        const int wid = t >> 6, lane = t & 63;
        const int b = HYP_K1 + (blk - G_BLOCKS) * 4 + wid;
        hyper_wave(z, opt, out, b, lane, hbuf[wid], hbuf[wid] + 64);
    }
}

// ---------- launcher ----------
extern "C" void kernel_launch(void* const* d_in, const int* in_sizes, int n_in,
                              void* d_out, int out_size, void* d_ws, size_t ws_size,
                              hipStream_t stream)
{
    const float* z   = (const float*)d_in[0];
    const float* opt = (const float*)d_in[1];
    const float* w1  = (const float*)d_in[2];
    const float* b1  = (const float*)d_in[3];
    const float* w2  = (const float*)d_in[4];
    const float* b2  = (const float*)d_in[5];
    const float* w3  = (const float*)d_in[6];
    const float* b3  = (const float*)d_in[7];
    float* out = (float*)d_out;

    __hip_bfloat16* T1   = (__hip_bfloat16*)d_ws;  // 8 MB
    __hip_bfloat16* w2bf = (__hip_bfloat16*)((char*)d_ws +
                             (size_t)B_SZ * H_DIM * sizeof(__hip_bfloat16));  // 2 MB

    k1_kernel<<<dim3(G_BLOCKS + CONV_BLOCKS + HYP_K1 / 4), dim3(256), 0, stream>>>(
        z, opt, w1, b1, w2, b3, T1, w2bf, out);

    k2_kernel<<<dim3(G_BLOCKS + (B_SZ - HYP_K1) / 4), dim3(256), 0, stream>>>(
        z, opt, T1, w2bf, b2, w3, out);
}